// Round 2
// baseline (307.731 us; speedup 1.0000x reference)
//
#include <hip/hip_runtime.h>
#include <hip/hip_bf16.h>

// Linear attention: out = S * (qe·KV) / (qe·ksum + 1e-6), qe/ke = elu(x)+1, masked.
// B=4 H=8 S=8192 D=64. q,k,v,out: float32. masks: int32 (0/1).

#define S_LEN 8192
#define NBH 32           // B*H
#define DIM 64
#define KVSTRIDE (64*64 + 64)   // KV matrix + ksum per (b,h)
#define MAXCHUNK 16

__device__ __forceinline__ float elu1(float x) {
  // elu(x)+1 : x>0 -> x+1 ; x<=0 -> exp(x)
  return x > 0.0f ? (x + 1.0f) : __expf(x);
}

// ---------------- Phase 1: partial KV + ksum over a segment of S ----------------
__global__ __launch_bounds__(256) void k1_partial(
    const float* __restrict__ kin, const float* __restrict__ vin,
    const int* __restrict__ kv_mask, float* __restrict__ partials, int seg_rows) {
  __shared__ float ke_s[64][64];
  __shared__ float ve_s[64][64];
  const int tid = threadIdx.x;
  const int seg = blockIdx.x, bh = blockIdx.y, b = bh >> 3;   // H=8
  const int dg = tid >> 4, cg = tid & 15;
  float acc[4][4] = {};
  float ks[4] = {};
  const int rbase = seg * seg_rows;

  for (int t0 = 0; t0 < seg_rows; t0 += 64) {
    const int r0 = rbase + t0;
    const float4* kp = (const float4*)(kin + ((size_t)bh * S_LEN + r0) * DIM);
    const float4* vp = (const float4*)(vin + ((size_t)bh * S_LEN + r0) * DIM);
#pragma unroll
    for (int i = 0; i < 4; ++i) {
      int qd = i * 256 + tid;            // float4 index 0..1023
      int sl = qd >> 4, d = (qd & 15) * 4;
      float m = kv_mask[b * S_LEN + r0 + sl] ? 1.0f : 0.0f;
      float4 kw = kp[qd];
      float4 vw = vp[qd];
      float4 kf, vf;
      kf.x = elu1(kw.x) * m;
      kf.y = elu1(kw.y) * m;
      kf.z = elu1(kw.z) * m;
      kf.w = elu1(kw.w) * m;
      float mv = m * (1.0f / 8192.0f);   // reference folds /S into ve
      vf.x = vw.x * mv;
      vf.y = vw.y * mv;
      vf.z = vw.z * mv;
      vf.w = vw.w * mv;
      *(float4*)&ke_s[sl][d] = kf;       // contiguous across lanes: conflict-free
      *(float4*)&ve_s[sl][d] = vf;
    }
    __syncthreads();
#pragma unroll 4
    for (int s = 0; s < 64; ++s) {
      float4 kd = *(const float4*)&ke_s[s][dg * 4];
      float4 vq = *(const float4*)&ve_s[s][cg * 4];
      float ka[4] = {kd.x, kd.y, kd.z, kd.w};
      float va[4] = {vq.x, vq.y, vq.z, vq.w};
#pragma unroll
      for (int i2 = 0; i2 < 4; ++i2) {
        ks[i2] += ka[i2];                // redundant across cg; consistent values
#pragma unroll
        for (int j = 0; j < 4; ++j) acc[i2][j] += ka[i2] * va[j];
      }
    }
    __syncthreads();                     // protect LDS before next stage
  }

  float* p = partials + ((size_t)bh * gridDim.x + seg) * KVSTRIDE;
#pragma unroll
  for (int i2 = 0; i2 < 4; ++i2)
#pragma unroll
    for (int j = 0; j < 4; ++j)
      p[(dg * 4 + i2) * 64 + cg * 4 + j] = acc[i2][j];
  if (cg == 0) {
#pragma unroll
    for (int i2 = 0; i2 < 4; ++i2) p[4096 + dg * 4 + i2] = ks[i2];
  }
}

// ---------------- Phase 2: reduce partials -> final KV + ksum ----------------
__global__ __launch_bounds__(256) void k2_reduce(const float* __restrict__ partials,
                                                 float* __restrict__ kvfinal, int nchunk) {
  const int bh = blockIdx.x, tid = threadIdx.x;
  for (int idx = tid; idx < KVSTRIDE; idx += 256) {
    float s = 0.f;
    for (int c = 0; c < nchunk; ++c)
      s += partials[((size_t)bh * nchunk + c) * KVSTRIDE + idx];
    kvfinal[(size_t)bh * KVSTRIDE + idx] = s;
  }
}

// ---------------- Phase 3: out = S * (qe·KV) / (qe·ksum + 1e-6) ----------------
__global__ __launch_bounds__(256) void k3_out(
    const float* __restrict__ qin, const int* __restrict__ q_mask,
    const float* __restrict__ kvfinal, float* __restrict__ out) {
  __shared__ float kv_s[64][64];
  __shared__ float ksum_s[64];
  __shared__ float qeT[64][68];          // [d][row], stride 68 keeps float4 align + spreads banks
  const int tid = threadIdx.x;
  const int rb = blockIdx.x, bh = blockIdx.y, b = bh >> 3;
  const int r0 = rb * 64;
  const float* kvp = kvfinal + (size_t)bh * KVSTRIDE;
#pragma unroll
  for (int i = 0; i < 16; ++i) {
    int idx = i * 256 + tid;
    kv_s[idx >> 6][idx & 63] = kvp[idx];
  }
  if (tid < 64) ksum_s[tid] = kvp[4096 + tid];
  const float4* qp = (const float4*)(qin + ((size_t)bh * S_LEN + r0) * DIM);
#pragma unroll
  for (int i = 0; i < 4; ++i) {
    int qd = i * 256 + tid;
    int rl = qd >> 4, d = (qd & 15) * 4;
    float m = q_mask[b * S_LEN + r0 + rl] ? 1.0f : 0.0f;
    float4 qw = qp[qd];
    qeT[d][rl]     = elu1(qw.x) * m;
    qeT[d + 1][rl] = elu1(qw.y) * m;
    qeT[d + 2][rl] = elu1(qw.z) * m;
    qeT[d + 3][rl] = elu1(qw.w) * m;
  }
  __syncthreads();
  const int rg = tid >> 4, cg = tid & 15;
  float acc[4][4] = {};
  float den[4] = {};
#pragma unroll 4
  for (int d = 0; d < 64; ++d) {
    float4 qv  = *(const float4*)&qeT[d][rg * 4];
    float4 kvv = *(const float4*)&kv_s[d][cg * 4];
    float ksd = ksum_s[d];
    float qa[4] = {qv.x, qv.y, qv.z, qv.w};
    float ca[4] = {kvv.x, kvv.y, kvv.z, kvv.w};
#pragma unroll
    for (int i2 = 0; i2 < 4; ++i2) {
      den[i2] += qa[i2] * ksd;           // redundant across cg; bit-identical per row
#pragma unroll
      for (int j = 0; j < 4; ++j) acc[i2][j] += qa[i2] * ca[j];
    }
  }
#pragma unroll
  for (int i2 = 0; i2 < 4; ++i2) {
    int r = r0 + rg * 4 + i2;
    float inv = 8192.0f / (den[i2] + 1e-6f);
    float4 o;
    o.x = acc[i2][0] * inv;
    o.y = acc[i2][1] * inv;
    o.z = acc[i2][2] * inv;
    o.w = acc[i2][3] * inv;
    *(float4*)(out + ((size_t)bh * S_LEN + r) * DIM + cg * 4) = o;
  }
}

extern "C" void kernel_launch(void* const* d_in, const int* in_sizes, int n_in,
                              void* d_out, int out_size, void* d_ws, size_t ws_size,
                              hipStream_t stream) {
  const float* q = (const float*)d_in[0];
  const float* k = (const float*)d_in[1];
  const float* v = (const float*)d_in[2];
  const int* qm = (const int*)d_in[3];
  const int* km = (const int*)d_in[4];
  float* out = (float*)d_out;

  int nchunk = MAXCHUNK;
  while (nchunk > 1 &&
         ((size_t)NBH * (nchunk + 1) * KVSTRIDE * sizeof(float)) > ws_size)
    nchunk >>= 1;
  float* partials = (float*)d_ws;                               // [NBH][nchunk][KVSTRIDE]
  float* kvfinal  = partials + (size_t)NBH * nchunk * KVSTRIDE; // [NBH][KVSTRIDE]
  int seg_rows = S_LEN / nchunk;

  k1_partial<<<dim3(nchunk, NBH), 256, 0, stream>>>(k, v, km, partials, seg_rows);
  k2_reduce<<<dim3(NBH), 256, 0, stream>>>(partials, kvfinal, nchunk);
  k3_out<<<dim3(S_LEN / 64, NBH), 256, 0, stream>>>(q, qm, kvfinal, out);
}

// Round 3
// 247.924 us; speedup vs baseline: 1.2412x; 1.2412x over previous
//
#include <hip/hip_runtime.h>
#include <hip/hip_bf16.h>

// Linear attention: out = S * (qe·KV) / (qe·ksum + 1e-6), qe/ke = elu(x)+1, masked.
// B=4 H=8 S=8192 D=64. q,k,v,out: float32. masks: int32 (0/1).

#define S_LEN 8192
#define NBH 32           // B*H
#define DIM 64
#define KVSTRIDE (64*64 + 64)   // KV matrix + ksum per (b,h)
#define MAXCHUNK 32

__device__ __forceinline__ float elu1(float x) {
  // elu(x)+1 : x>0 -> x+1 ; x<=0 -> exp(x)
  return x > 0.0f ? (x + 1.0f) : __expf(x);
}

// ---------------- Phase 1: partial KV + ksum over a segment of S ----------------
__global__ __launch_bounds__(256) void k1_partial(
    const float* __restrict__ kin, const float* __restrict__ vin,
    const int* __restrict__ kv_mask, float* __restrict__ partials, int seg_rows) {
  __shared__ float ke_s[64][64];
  __shared__ float ve_s[64][64];
  const int tid = threadIdx.x;
  const int seg = blockIdx.x, bh = blockIdx.y, b = bh >> 3;   // H=8
  const int dg = tid >> 4, cg = tid & 15;
  float acc[4][4] = {};
  float ks[4] = {};
  const int rbase = seg * seg_rows;

  for (int t0 = 0; t0 < seg_rows; t0 += 64) {
    const int r0 = rbase + t0;
    const float4* kp = (const float4*)(kin + ((size_t)bh * S_LEN + r0) * DIM);
    const float4* vp = (const float4*)(vin + ((size_t)bh * S_LEN + r0) * DIM);
#pragma unroll
    for (int i = 0; i < 4; ++i) {
      int qd = i * 256 + tid;            // float4 index 0..1023
      int sl = qd >> 4, d = (qd & 15) * 4;
      float m = kv_mask[b * S_LEN + r0 + sl] ? 1.0f : 0.0f;
      float4 kw = kp[qd];
      float4 vw = vp[qd];
      float4 kf, vf;
      kf.x = elu1(kw.x) * m;
      kf.y = elu1(kw.y) * m;
      kf.z = elu1(kw.z) * m;
      kf.w = elu1(kw.w) * m;
      float mv = m * (1.0f / 8192.0f);   // reference folds /S into ve
      vf.x = vw.x * mv;
      vf.y = vw.y * mv;
      vf.z = vw.z * mv;
      vf.w = vw.w * mv;
      *(float4*)&ke_s[sl][d] = kf;       // contiguous across lanes: conflict-free
      *(float4*)&ve_s[sl][d] = vf;
    }
    __syncthreads();
#pragma unroll 4
    for (int s = 0; s < 64; ++s) {
      float4 kd = *(const float4*)&ke_s[s][dg * 4];
      float4 vq = *(const float4*)&ve_s[s][cg * 4];
      float ka[4] = {kd.x, kd.y, kd.z, kd.w};
      float va[4] = {vq.x, vq.y, vq.z, vq.w};
#pragma unroll
      for (int i2 = 0; i2 < 4; ++i2) {
        ks[i2] += ka[i2];                // redundant across cg; consistent values
#pragma unroll
        for (int j = 0; j < 4; ++j) acc[i2][j] += ka[i2] * va[j];
      }
    }
    __syncthreads();                     // protect LDS before next stage
  }

  float* p = partials + ((size_t)bh * gridDim.x + seg) * KVSTRIDE;
#pragma unroll
  for (int i2 = 0; i2 < 4; ++i2)
#pragma unroll
    for (int j = 0; j < 4; ++j)
      p[(dg * 4 + i2) * 64 + cg * 4 + j] = acc[i2][j];
  if (cg == 0) {
#pragma unroll
    for (int i2 = 0; i2 < 4; ++i2) p[4096 + dg * 4 + i2] = ks[i2];
  }
}

// ---------------- Phase 2: reduce partials -> final KV + ksum (wide grid) ----------------
__global__ __launch_bounds__(256) void k2_reduce(const float* __restrict__ partials,
                                                 float* __restrict__ kvfinal, int nchunk) {
  const int idx = blockIdx.x * 256 + threadIdx.x;       // one thread per output element
  if (idx >= NBH * KVSTRIDE) return;
  const int bh = idx / KVSTRIDE;
  const int e  = idx - bh * KVSTRIDE;
  const float* p = partials + (size_t)bh * nchunk * KVSTRIDE + e;
  float s0 = 0.f, s1 = 0.f, s2 = 0.f, s3 = 0.f;
  int c = 0;
  for (; c + 4 <= nchunk; c += 4) {       // 4 independent accumulators for ILP
    s0 += p[(size_t)(c + 0) * KVSTRIDE];
    s1 += p[(size_t)(c + 1) * KVSTRIDE];
    s2 += p[(size_t)(c + 2) * KVSTRIDE];
    s3 += p[(size_t)(c + 3) * KVSTRIDE];
  }
  for (; c < nchunk; ++c) s0 += p[(size_t)c * KVSTRIDE];
  kvfinal[(size_t)bh * KVSTRIDE + e] = (s0 + s1) + (s2 + s3);
}

// ---------------- Phase 3: out = S * (qe·KV) / (qe·ksum + 1e-6) ----------------
__global__ __launch_bounds__(256) void k3_out(
    const float* __restrict__ qin, const int* __restrict__ q_mask,
    const float* __restrict__ kvfinal, float* __restrict__ out) {
  __shared__ float kv_s[64][64];
  __shared__ float ksum_s[64];
  __shared__ float qeT[64][68];          // [d][row], stride 68 keeps float4 align + spreads banks
  const int tid = threadIdx.x;
  const int rb = blockIdx.x, bh = blockIdx.y, b = bh >> 3;
  const int r0 = rb * 64;
  const float* kvp = kvfinal + (size_t)bh * KVSTRIDE;
#pragma unroll
  for (int i = 0; i < 16; ++i) {
    int idx = i * 256 + tid;
    kv_s[idx >> 6][idx & 63] = kvp[idx];
  }
  if (tid < 64) ksum_s[tid] = kvp[4096 + tid];
  const float4* qp = (const float4*)(qin + ((size_t)bh * S_LEN + r0) * DIM);
#pragma unroll
  for (int i = 0; i < 4; ++i) {
    int qd = i * 256 + tid;
    int rl = qd >> 4, d = (qd & 15) * 4;
    float m = q_mask[b * S_LEN + r0 + rl] ? 1.0f : 0.0f;
    float4 qw = qp[qd];
    qeT[d][rl]     = elu1(qw.x) * m;
    qeT[d + 1][rl] = elu1(qw.y) * m;
    qeT[d + 2][rl] = elu1(qw.z) * m;
    qeT[d + 3][rl] = elu1(qw.w) * m;
  }
  __syncthreads();
  const int rg = tid >> 4, cg = tid & 15;
  float acc[4][4] = {};
  float den[4] = {};
#pragma unroll 4
  for (int d = 0; d < 64; ++d) {
    float4 qv  = *(const float4*)&qeT[d][rg * 4];
    float4 kvv = *(const float4*)&kv_s[d][cg * 4];
    float ksd = ksum_s[d];
    float qa[4] = {qv.x, qv.y, qv.z, qv.w};
    float ca[4] = {kvv.x, kvv.y, kvv.z, kvv.w};
#pragma unroll
    for (int i2 = 0; i2 < 4; ++i2) {
      den[i2] += qa[i2] * ksd;           // redundant across cg; bit-identical per row
#pragma unroll
      for (int j = 0; j < 4; ++j) acc[i2][j] += qa[i2] * ca[j];
    }
  }
#pragma unroll
  for (int i2 = 0; i2 < 4; ++i2) {
    int r = r0 + rg * 4 + i2;
    float inv = 8192.0f / (den[i2] + 1e-6f);
    float4 o;
    o.x = acc[i2][0] * inv;
    o.y = acc[i2][1] * inv;
    o.z = acc[i2][2] * inv;
    o.w = acc[i2][3] * inv;
    *(float4*)(out + ((size_t)bh * S_LEN + r) * DIM + cg * 4) = o;
  }
}

extern "C" void kernel_launch(void* const* d_in, const int* in_sizes, int n_in,
                              void* d_out, int out_size, void* d_ws, size_t ws_size,
                              hipStream_t stream) {
  const float* q = (const float*)d_in[0];
  const float* k = (const float*)d_in[1];
  const float* v = (const float*)d_in[2];
  const int* qm = (const int*)d_in[3];
  const int* km = (const int*)d_in[4];
  float* out = (float*)d_out;

  int nchunk = MAXCHUNK;
  while (nchunk > 1 &&
         ((size_t)NBH * (nchunk + 1) * KVSTRIDE * sizeof(float)) > ws_size)
    nchunk >>= 1;
  float* partials = (float*)d_ws;                               // [NBH][nchunk][KVSTRIDE]
  float* kvfinal  = partials + (size_t)NBH * nchunk * KVSTRIDE; // [NBH][KVSTRIDE]
  int seg_rows = S_LEN / nchunk;

  k1_partial<<<dim3(nchunk, NBH), 256, 0, stream>>>(k, v, km, partials, seg_rows);
  int n_elem = NBH * KVSTRIDE;
  k2_reduce<<<dim3((n_elem + 255) / 256), 256, 0, stream>>>(partials, kvfinal, nchunk);
  k3_out<<<dim3(S_LEN / 64, NBH), 256, 0, stream>>>(q, qm, kvfinal, out);
}

// Round 4
// 238.525 us; speedup vs baseline: 1.2901x; 1.0394x over previous
//
#include <hip/hip_runtime.h>
#include <hip/hip_bf16.h>

// Linear attention via MFMA (bf16 hi/lo split for ~fp32 precision).
// out = S * (qe.KV) / (qe.ksum + 1e-6);  qe/ke = elu(x)+1, masked.
// B=4 H=8 S=8192 D=64. q,k,v,out: float32. masks: int32 (0/1).

#define S_LEN 8192
#define NBH 32
#define KVSTRIDE 4160          // 64*64 KV + 64 ksum (fp32 partials)

typedef __attribute__((ext_vector_type(8))) short short8;
typedef __attribute__((ext_vector_type(4))) float f32x4;

__device__ __forceinline__ float elu1(float x) {
  return x > 0.0f ? (x + 1.0f) : __expf(x);
}
__device__ __forceinline__ unsigned short f2bf(float x) {
  __hip_bfloat16 h = __float2bfloat16(x);
  union { __hip_bfloat16 b; unsigned short u; } cv; cv.b = h; return cv.u;
}
__device__ __forceinline__ float bf2f(unsigned short u) {
  return __uint_as_float(((unsigned)u) << 16);
}
// x ~= hi + lo with hi,lo bf16; residual ~2^-17 relative.
__device__ __forceinline__ void split2(float x, unsigned short& hi, unsigned short& lo) {
  hi = f2bf(x);
  lo = f2bf(x - bf2f(hi));      // subtraction exact in fp32 (Sterbenz)
}
__device__ __forceinline__ short8 ones8() {
  short8 o;
#pragma unroll
  for (int i = 0; i < 8; ++i) o[i] = (short)0x3F80;   // bf16 1.0
  return o;
}

#define MFMA(a,b,c) __builtin_amdgcn_mfma_f32_16x16x32_bf16((a),(b),(c),0,0,0)

// ---------------- Phase 1: partial KV + ksum over a segment of S (MFMA) ----------------
// A = keT[d][s] (M=d), B = veT -> read as B[k=s][n=c] from [c][s] layout. K = s.
__global__ __launch_bounds__(256) void k1_partial(
    const float* __restrict__ kin, const float* __restrict__ vin,
    const int* __restrict__ kv_mask, float* __restrict__ partials, int seg_rows) {
  __shared__ unsigned short keT_h[64 * 72];   // [d][s], stride 72 (144B rows: 16B-aligned frags)
  __shared__ unsigned short keT_l[64 * 72];
  __shared__ unsigned short veT_h[64 * 72];   // [c][s]
  __shared__ unsigned short veT_l[64 * 72];
  const int tid = threadIdx.x;
  const int seg = blockIdx.x, bh = blockIdx.y, b = bh >> 3;   // H=8
  const int dp = tid & 31;      // feature pair: d = 2*dp, 2*dp+1
  const int so = tid >> 5;      // s-octet: s = so*8 + r
  const int lane = tid & 63, w = tid >> 6;
  const int mrow = lane & 15, qd4 = lane >> 4;
  const short8 one = ones8();

  f32x4 acc[4]; f32x4 accs;
#pragma unroll
  for (int t = 0; t < 4; ++t) acc[t] = (f32x4){0.f, 0.f, 0.f, 0.f};
  accs = (f32x4){0.f, 0.f, 0.f, 0.f};

  const int rbase = seg * seg_rows;
  for (int t0 = 0; t0 < seg_rows; t0 += 64) {
    const int r0 = rbase + t0;
    // ---- stage: load 8s x 2d, transpose in regs, split, write bf16 planes ----
    const float* kp = kin + ((size_t)bh * S_LEN + r0 + so * 8) * 64 + dp * 2;
    const float* vp = vin + ((size_t)bh * S_LEN + r0 + so * 8) * 64 + dp * 2;
    union { unsigned short u[8]; uint4 v; } kh0, kh1, kl0, kl1, vh0, vh1, vl0, vl1;
#pragma unroll
    for (int r = 0; r < 8; ++r) {
      float m = kv_mask[b * S_LEN + r0 + so * 8 + r] ? 1.0f : 0.0f;
      float2 kw = *(const float2*)(kp + (size_t)r * 64);
      float2 vw = *(const float2*)(vp + (size_t)r * 64);
      float ka = elu1(kw.x) * m;
      float kb = elu1(kw.y) * m;
      float mv = m * (1.0f / 8192.0f);    // reference folds /S into ve
      float va = vw.x * mv, vb = vw.y * mv;
      split2(ka, kh0.u[r], kl0.u[r]);
      split2(kb, kh1.u[r], kl1.u[r]);
      split2(va, vh0.u[r], vl0.u[r]);
      split2(vb, vh1.u[r], vl1.u[r]);
    }
    const int d0 = dp * 2;
    *(uint4*)&keT_h[(d0    ) * 72 + so * 8] = kh0.v;
    *(uint4*)&keT_h[(d0 + 1) * 72 + so * 8] = kh1.v;
    *(uint4*)&keT_l[(d0    ) * 72 + so * 8] = kl0.v;
    *(uint4*)&keT_l[(d0 + 1) * 72 + so * 8] = kl1.v;
    *(uint4*)&veT_h[(d0    ) * 72 + so * 8] = vh0.v;
    *(uint4*)&veT_h[(d0 + 1) * 72 + so * 8] = vh1.v;
    *(uint4*)&veT_l[(d0    ) * 72 + so * 8] = vl0.v;
    *(uint4*)&veT_l[(d0 + 1) * 72 + so * 8] = vl1.v;
    __syncthreads();
    // ---- MFMA: wave w owns d-stripe [w*16, w*16+16) x all 64 c ----
#pragma unroll
    for (int k0 = 0; k0 < 64; k0 += 32) {
      short8 a_h = *(const short8*)&keT_h[(w * 16 + mrow) * 72 + k0 + qd4 * 8];
      short8 a_l = *(const short8*)&keT_l[(w * 16 + mrow) * 72 + k0 + qd4 * 8];
      accs = MFMA(a_h, one, accs);                 // ksum[d] = sum_s ke
      accs = MFMA(a_l, one, accs);
#pragma unroll
      for (int t = 0; t < 4; ++t) {
        short8 b_h = *(const short8*)&veT_h[(t * 16 + mrow) * 72 + k0 + qd4 * 8];
        short8 b_l = *(const short8*)&veT_l[(t * 16 + mrow) * 72 + k0 + qd4 * 8];
        acc[t] = MFMA(a_h, b_h, acc[t]);
        acc[t] = MFMA(a_h, b_l, acc[t]);
        acc[t] = MFMA(a_l, b_h, acc[t]);
      }
    }
    __syncthreads();
  }
  // store partial KV [d][c] fp32 + ksum; C/D layout: row=(lane>>4)*4+reg, col=lane&15
  float* p = partials + ((size_t)bh * gridDim.x + seg) * KVSTRIDE;
#pragma unroll
  for (int t = 0; t < 4; ++t)
#pragma unroll
    for (int r = 0; r < 4; ++r)
      p[(w * 16 + qd4 * 4 + r) * 64 + t * 16 + mrow] = acc[t][r];
  if (mrow == 0) {
#pragma unroll
    for (int r = 0; r < 4; ++r) p[4096 + w * 16 + qd4 * 4 + r] = accs[r];
  }
}

// ---------------- Phase 2: reduce partials -> bf16 hi/lo KV^T planes + split ksum ----------------
__global__ __launch_bounds__(256) void k2_reduce(
    const float* __restrict__ partials,
    unsigned short* __restrict__ kvTh, unsigned short* __restrict__ kvTl,
    unsigned short* __restrict__ ksh, unsigned short* __restrict__ ksl, int nchunk) {
  const int idx = blockIdx.x * 256 + threadIdx.x;
  if (idx >= NBH * KVSTRIDE) return;
  const int bh = idx / KVSTRIDE;
  const int e = idx - bh * KVSTRIDE;
  const float* p = partials + (size_t)bh * nchunk * KVSTRIDE + e;
  float s0 = 0.f, s1 = 0.f, s2 = 0.f, s3 = 0.f;
  int c = 0;
  for (; c + 4 <= nchunk; c += 4) {
    s0 += p[(size_t)(c + 0) * KVSTRIDE];
    s1 += p[(size_t)(c + 1) * KVSTRIDE];
    s2 += p[(size_t)(c + 2) * KVSTRIDE];
    s3 += p[(size_t)(c + 3) * KVSTRIDE];
  }
  for (; c < nchunk; ++c) s0 += p[(size_t)c * KVSTRIDE];
  float s = (s0 + s1) + (s2 + s3);
  unsigned short hi, lo;
  split2(s, hi, lo);
  if (e < 4096) {
    int d = e >> 6, cc = e & 63;
    kvTh[(size_t)bh * 4096 + cc * 64 + d] = hi;   // transposed: [c][d]
    kvTl[(size_t)bh * 4096 + cc * 64 + d] = lo;
  } else {
    int d = e - 4096;
    ksh[bh * 64 + d] = hi;
    ksl[bh * 64 + d] = lo;
  }
}

// ---------------- Phase 3: out = S * (qe.KV) / (qe.ksum + 1e-6) (MFMA) ----------------
// A = qe[l][d] (natural layout), B = KV^T[c][d] read as B[k=d][n=c]. K = d.
__global__ __launch_bounds__(256) void k3_out(
    const float* __restrict__ qin, const int* __restrict__ q_mask,
    const unsigned short* __restrict__ kvTh_g, const unsigned short* __restrict__ kvTl_g,
    const unsigned short* __restrict__ ksh_g, const unsigned short* __restrict__ ksl_g,
    float* __restrict__ out) {
  __shared__ unsigned short qe_h[64 * 72];    // [l][d]
  __shared__ unsigned short qe_l[64 * 72];
  __shared__ unsigned short kv_h[64 * 72];    // [c][d]
  __shared__ unsigned short kv_l[64 * 72];
  __shared__ __align__(16) unsigned short ks_h[64];
  __shared__ __align__(16) unsigned short ks_l[64];
  const int tid = threadIdx.x;
  const int rb = blockIdx.x, bh = blockIdx.y, b = bh >> 3;
  const int r0 = rb * 64;
  // stage qe (elu+mask+split); no transpose needed
#pragma unroll
  for (int i = 0; i < 4; ++i) {
    int qd = i * 256 + tid;
    int l = qd >> 4, dq = qd & 15;
    float m = q_mask[b * S_LEN + r0 + l] ? 1.0f : 0.0f;
    float4 qw = *(const float4*)(qin + ((size_t)bh * S_LEN + r0 + l) * 64 + dq * 4);
    union { unsigned short u[4]; uint2 v; } h, lo;
    float e0 = elu1(qw.x) * m, e1 = elu1(qw.y) * m, e2 = elu1(qw.z) * m, e3 = elu1(qw.w) * m;
    split2(e0, h.u[0], lo.u[0]);
    split2(e1, h.u[1], lo.u[1]);
    split2(e2, h.u[2], lo.u[2]);
    split2(e3, h.u[3], lo.u[3]);
    *(uint2*)&qe_h[l * 72 + dq * 4] = h.v;
    *(uint2*)&qe_l[l * 72 + dq * 4] = lo.v;
  }
  // stage KV^T planes (tiny, L2-resident) + ksum
  for (int e = tid; e < 2048; e += 256) {
    int c = (e * 2) >> 6, d = (e * 2) & 63;
    *(unsigned*)&kv_h[c * 72 + d] = *(const unsigned*)(kvTh_g + (size_t)bh * 4096 + e * 2);
    *(unsigned*)&kv_l[c * 72 + d] = *(const unsigned*)(kvTl_g + (size_t)bh * 4096 + e * 2);
  }
  if (tid < 64) {
    ks_h[tid] = ksh_g[bh * 64 + tid];
    ks_l[tid] = ksl_g[bh * 64 + tid];
  }
  __syncthreads();
  const int lane = tid & 63, w = tid >> 6;
  const int mrow = lane & 15, qd4 = lane >> 4;
  f32x4 acc[4]; f32x4 accd;
#pragma unroll
  for (int t = 0; t < 4; ++t) acc[t] = (f32x4){0.f, 0.f, 0.f, 0.f};
  accd = (f32x4){0.f, 0.f, 0.f, 0.f};
#pragma unroll
  for (int k0 = 0; k0 < 64; k0 += 32) {
    short8 a_h = *(const short8*)&qe_h[(w * 16 + mrow) * 72 + k0 + qd4 * 8];
    short8 a_l = *(const short8*)&qe_l[(w * 16 + mrow) * 72 + k0 + qd4 * 8];
    short8 s_h = *(const short8*)&ks_h[k0 + qd4 * 8];   // broadcast over n
    short8 s_l = *(const short8*)&ks_l[k0 + qd4 * 8];
    accd = MFMA(a_h, s_h, accd);      // den[l] in every column
    accd = MFMA(a_h, s_l, accd);
    accd = MFMA(a_l, s_h, accd);
#pragma unroll
    for (int t = 0; t < 4; ++t) {
      short8 b_h = *(const short8*)&kv_h[(t * 16 + mrow) * 72 + k0 + qd4 * 8];
      short8 b_l = *(const short8*)&kv_l[(t * 16 + mrow) * 72 + k0 + qd4 * 8];
      acc[t] = MFMA(a_h, b_h, acc[t]);
      acc[t] = MFMA(a_h, b_l, acc[t]);
      acc[t] = MFMA(a_l, b_h, acc[t]);
    }
  }
  // epilogue: den rows align with acc rows (C-layout) -> lane-local divide
#pragma unroll
  for (int r = 0; r < 4; ++r) {
    float inv = 8192.0f / (accd[r] + 1e-6f);
    int row = r0 + w * 16 + qd4 * 4 + r;
#pragma unroll
    for (int t = 0; t < 4; ++t)
      out[((size_t)bh * S_LEN + row) * 64 + t * 16 + mrow] = acc[t][r] * inv;
  }
}

extern "C" void kernel_launch(void* const* d_in, const int* in_sizes, int n_in,
                              void* d_out, int out_size, void* d_ws, size_t ws_size,
                              hipStream_t stream) {
  const float* q = (const float*)d_in[0];
  const float* k = (const float*)d_in[1];
  const float* v = (const float*)d_in[2];
  const int* qm = (const int*)d_in[3];
  const int* km = (const int*)d_in[4];
  float* out = (float*)d_out;

  int nchunk = 32;
  while (nchunk > 1) {
    size_t need = (size_t)NBH * nchunk * KVSTRIDE * 4
                + (size_t)NBH * 4096 * 2 * 2 + (size_t)NBH * 64 * 2 * 2;
    if (need <= ws_size) break;
    nchunk >>= 1;
  }
  float* partials = (float*)d_ws;                                   // [NBH][nchunk][KVSTRIDE] f32
  unsigned short* kvTh = (unsigned short*)(partials + (size_t)NBH * nchunk * KVSTRIDE);
  unsigned short* kvTl = kvTh + (size_t)NBH * 4096;
  unsigned short* ksh  = kvTl + (size_t)NBH * 4096;
  unsigned short* ksl  = ksh + NBH * 64;
  int seg_rows = S_LEN / nchunk;

  k1_partial<<<dim3(nchunk, NBH), 256, 0, stream>>>(k, v, km, partials, seg_rows);
  int n_elem = NBH * KVSTRIDE;
  k2_reduce<<<dim3((n_elem + 255) / 256), 256, 0, stream>>>(partials, kvTh, kvTl, ksh, ksl, nchunk);
  k3_out<<<dim3(S_LEN / 64, NBH), 256, 0, stream>>>(q, qm, kvTh, kvTl, ksh, ksl, out);
}